// Round 4
// baseline (409.963 us; speedup 1.0000x reference)
//
#include <hip/hip_runtime.h>
#include <hip/hip_bf16.h>

#define kB 16
#define kS 2048
#define kD 1024
#define kH 128
#define kBS (kB * kS)

typedef short s8v __attribute__((ext_vector_type(8)));
typedef float f4v __attribute__((ext_vector_type(4)));
typedef float f16v __attribute__((ext_vector_type(16)));
typedef unsigned short us4 __attribute__((ext_vector_type(4)));
typedef unsigned short us8 __attribute__((ext_vector_type(8)));

__device__ __forceinline__ unsigned short f2bf(float f) {
    __hip_bfloat16 h = __float2bfloat16(f);
    return __builtin_bit_cast(unsigned short, h);
}

// async global->LDS DMA, 16B per lane, LDS dest = base + lane*16 (HW rule)
__device__ __forceinline__ void gl16(const void* g, void* l) {
    __builtin_amdgcn_global_load_lds(
        (const __attribute__((address_space(1))) unsigned int*)g,
        (__attribute__((address_space(3))) unsigned int*)l, 16, 0, 0);
}

// ---------------------------------------------------------------------------
// Kernel 0: W[1024][128] fp32 -> Wt[384][1024] bf16 (transposed, q|k|v).
// Wq pre-scaled by H^-0.5.  (unchanged)
// ---------------------------------------------------------------------------
__global__ void prep_w(const float* __restrict__ Wq, const float* __restrict__ Wk,
                       const float* __restrict__ Wv, unsigned short* __restrict__ Wt)
{
    const int g = blockIdx.x;
    const float* W = (g == 0) ? Wq : (g == 1) ? Wk : Wv;
    const float sc = (g == 0) ? 0.08838834764831845f : 1.0f;  // 128^-0.5 folded into Wq
    unsigned short* o = Wt + (size_t)g * 128 * 1024;
    const int t = threadIdx.x;
    const int n = t & 127;
    const int half = t >> 7;
    const int kbase = blockIdx.y * 64 + half * 32;
    #pragma unroll
    for (int c = 0; c < 4; ++c) {
        int kb = kbase + c * 8;
        us8 v;
        #pragma unroll
        for (int j = 0; j < 8; ++j) v[j] = f2bf(W[(size_t)(kb + j) * kH + n] * sc);
        *(us8*)(o + (size_t)n * 1024 + kb) = v;
    }
}

// ---------------------------------------------------------------------------
// Kernel 1 (R8): fused QKV GEMM — B staged via global_load_lds DMA (m97
// lever), A reg-staged fp32->bf16. LDS double-buffer, ONE barrier/K-step.
//  Per buffer (shorts): Bs[384][32] at 0 (linear — DMA requires it),
//  As[64][36] at 12288. Buffer stride 14592 sh. 2 buffers = 58368 B.
//  Per step/wave: 6 B-DMA issues + 2 A float4 loads + 1 A us8 ds_write;
//  then 10 ds_read_b128 + 24 MFMA. 512 blocks, 2/CU.
// ---------------------------------------------------------------------------
#define QBUF 14592

#define STAGE(buf_, tt_) do {                                                 \
    xa[0] = *(const float4*)(Xp + (tt_) * 32);                                \
    xa[1] = *(const float4*)(Xp + (tt_) * 32 + 4);                            \
    _Pragma("unroll")                                                         \
    for (int ci = 0; ci < 6; ++ci) {                                          \
        const int c = w + 4 * ci;                                             \
        gl16(Wp + (size_t)c * 16 * 1024 + (tt_) * 32,                         \
             &smem[(buf_) * QBUF + c * 512]);                                 \
    }                                                                         \
} while (0)

#define AWRITE(buf_) do {                                                     \
    us8 aw;                                                                   \
    aw[0] = f2bf(xa[0].x); aw[1] = f2bf(xa[0].y);                             \
    aw[2] = f2bf(xa[0].z); aw[3] = f2bf(xa[0].w);                             \
    aw[4] = f2bf(xa[1].x); aw[5] = f2bf(xa[1].y);                             \
    aw[6] = f2bf(xa[1].z); aw[7] = f2bf(xa[1].w);                             \
    *(us8*)&smem[(buf_) * QBUF + 12288 + arow * 36 + ac8] = aw;               \
} while (0)

__global__ __launch_bounds__(256, 2) void qkv_gemm(
    const float* __restrict__ X, const unsigned short* __restrict__ Wt,
    unsigned short* __restrict__ ws)
{
    __shared__ __align__(16) unsigned short smem[29184];

    const int t    = threadIdx.x;
    const int L    = t & 63;
    const int w    = t >> 6;                 // wave 0..3, owns cols w*96..+95
    const int col  = L & 15;
    const int quad = L >> 4;
    const int m0   = blockIdx.x * 64;

    f4v acc[4][6];
    #pragma unroll
    for (int i = 0; i < 4; ++i)
        #pragma unroll
        for (int j = 0; j < 6; ++j) { f4v z = {0.f, 0.f, 0.f, 0.f}; acc[i][j] = z; }

    const int arow = t >> 2;                 // 0..63
    const int ac8  = (t & 3) * 8;            // 0,8,16,24 (k within 32-slice)
    const float* Xp          = X  + (size_t)(m0 + arow) * kD + ac8;
    // DMA source: lane L covers row 16c + (L>>2), k-offset (L&3)*8 shorts
    const unsigned short* Wp = Wt + (size_t)(L >> 2) * 1024 + (L & 3) * 8;

    float4 xa[2];

    STAGE(0, 0);
    AWRITE(0);           // waits A loads (vmcnt leaves B DMAs in flight)
    __syncthreads();     // drains all (B DMA tile 0 complete)

    #pragma unroll 2
    for (int tt = 0; tt < 32; ++tt) {
        const int cb = (tt & 1) * QBUF;
        if (tt < 31) STAGE((tt + 1) & 1, tt + 1);   // fire-and-forget
        s8v Af[4], Bf[6];
        #pragma unroll
        for (int i = 0; i < 4; ++i)
            Af[i] = *(const s8v*)&smem[cb + 12288 + (i * 16 + col) * 36 + quad * 8];
        #pragma unroll
        for (int j = 0; j < 6; ++j)
            Bf[j] = *(const s8v*)&smem[cb + (w * 96 + j * 16 + col) * 32 + quad * 8];
        #pragma unroll
        for (int i = 0; i < 4; ++i)
            #pragma unroll
            for (int j = 0; j < 6; ++j)
                acc[i][j] = __builtin_amdgcn_mfma_f32_16x16x32_bf16(
                    Af[i], Bf[j], acc[i][j], 0, 0, 0);
        if (tt < 31) AWRITE((tt + 1) & 1);
        __syncthreads();
    }

    // ---- epilogue: repack via LDS, write q/k [s][h] and v^T [b][h][s] ----
    for (int g = 0; g < 3; ++g) {
        __syncthreads();
        #pragma unroll
        for (int j = 0; j < 6; ++j) {
            if (((96 * w + 16 * j) >> 7) != g) continue;   // wave-uniform
            int n = 96 * w + 16 * j + col;
            if (g < 2) {
                int ng = n - g * 128;
                #pragma unroll
                for (int i = 0; i < 4; ++i)
                    #pragma unroll
                    for (int rg = 0; rg < 4; ++rg)
                        smem[(i * 16 + quad * 4 + rg) * 136 + ng] = f2bf(acc[i][j][rg]);
            } else {
                int h = n - 256;
                #pragma unroll
                for (int i = 0; i < 4; ++i) {
                    us4 pk = { f2bf(acc[i][j][0]), f2bf(acc[i][j][1]),
                               f2bf(acc[i][j][2]), f2bf(acc[i][j][3]) };
                    *(us4*)&smem[h * 72 + i * 16 + quad * 4] = pk;   // Ts[h][s]
                }
            }
        }
        __syncthreads();
        if (g < 2) {
            unsigned short* outp = ws + (size_t)g * kBS * kH;
            int row = t >> 2, hc = (t & 3) * 32;
            #pragma unroll
            for (int u = 0; u < 4; ++u) {
                us8 v = *(const us8*)&smem[row * 136 + hc + u * 8];
                *(us8*)(outp + (size_t)(m0 + row) * kH + hc + u * 8) = v;
            }
        } else {
            unsigned short* vtp = ws + (size_t)2 * kBS * kH;
            int h = t >> 1, sb = (t & 1) * 32;
            int bb = m0 >> 11, sl = m0 & 2047;
            #pragma unroll
            for (int u = 0; u < 4; ++u) {
                us8 v = *(const us8*)&smem[h * 72 + sb + u * 8];
                *(us8*)(vtp + ((size_t)bb * kH + h) * kS + sl + sb + u * 8) = v;
            }
        }
    }
}

// ---------------------------------------------------------------------------
// Kernel 2 (R8): causal attention — 4-wave SPLIT-K per q-slot. Wave w takes
// key tiles T ≡ w (mod 4); plain-exp streaming softmax means partial O and
// partial l combine by pure addition (chunked LDS reduction at the end).
// Occupancy: 1024 blocks x 4 waves = 16 waves/CU (was 4).
// ---------------------------------------------------------------------------
__global__ __launch_bounds__(256, 4) void attn(
    const unsigned short* __restrict__ ws, float* __restrict__ out)
{
    __shared__ float Ob[4096];               // 16 KB combine chunk
    __shared__ float Lsums[128];
    __shared__ unsigned short Ps[4 * 1152];  // per-wave P[32][36]

    const int t   = threadIdx.x;
    const int w   = t >> 6;                  // wave 0..3
    const int L   = t & 63;
    const int l5  = L >> 5;
    const int c32 = L & 31;
    const int b   = blockIdx.x;
    const int g2  = blockIdx.y >> 4, ii = blockIdx.y & 15;
    const int s   = (g2 == 0) ? 63 - ii : (g2 == 1) ? 32 + ii
                  : (g2 == 2) ? 31 - ii : ii;          // bijective onto 0..63

    const unsigned short* qp = ws;
    const unsigned short* kp = ws + (size_t)kBS * kH + (size_t)b * kS * kH;
    const unsigned short* vt = ws + (size_t)2 * kBS * kH + (size_t)b * kH * kS;

    const size_t qrow = (size_t)b * kS + s * 32 + c32;
    unsigned short* myPs = Ps + w * 1152;

    // Q B-frags (n=lane&31 -> q=c32, k=l5*8+j at k-offset ks*16)
    s8v Qf[8];
    #pragma unroll
    for (int ks = 0; ks < 8; ++ks)
        Qf[ks] = *(const s8v*)(qp + qrow * kH + ks * 16 + l5 * 8);

    f16v O[4];
    #pragma unroll
    for (int nt = 0; nt < 4; ++nt)
        #pragma unroll
        for (int r = 0; r < 16; ++r) O[nt][r] = 0.f;
    float lsum = 0.f;

    // prefetch first K tile of this wave (rows w*32.. always in-bounds)
    s8v Kf[8];
    #pragma unroll
    for (int ks = 0; ks < 8; ++ks)
        Kf[ks] = *(const s8v*)(kp + (size_t)(w * 32 + c32) * kH + ks * 16 + l5 * 8);

    for (int T = w; T <= s; T += 4) {
        const int kb = T * 32;
        // V^T A-frags (m = h within 32-group = c32, k = key)
        s8v Vf[2][4];
        #pragma unroll
        for (int k2 = 0; k2 < 2; ++k2)
            #pragma unroll
            for (int nt = 0; nt < 4; ++nt)
                Vf[k2][nt] = *(const s8v*)(vt + (size_t)(nt * 32 + c32) * kS
                                           + kb + k2 * 16 + l5 * 8);
        // S^T = K Q^T
        f16v Sv;
        #pragma unroll
        for (int r = 0; r < 16; ++r) Sv[r] = 0.f;
        #pragma unroll
        for (int ks = 0; ks < 8; ++ks)
            Sv = __builtin_amdgcn_mfma_f32_32x32x16_bf16(Kf[ks], Qf[ks], Sv, 0, 0, 0);
        // prefetch this wave's next K tile (stride 4 tiles = +128 rows)
        if (T + 4 <= s) {
            #pragma unroll
            for (int ks = 0; ks < 8; ++ks)
                Kf[ks] = *(const s8v*)(kp + (size_t)(kb + 128 + c32) * kH + ks * 16 + l5 * 8);
        }
        // mask (diagonal tile) + exp + P store; lane holds 16 keys of q=c32
        const bool dm = (T == s);
        #pragma unroll
        for (int g4 = 0; g4 < 4; ++g4) {
            us4 pk;
            #pragma unroll
            for (int u = 0; u < 4; ++u) {
                int krow = u + 8 * g4 + 4 * l5;       // C-layout row = key
                float v = Sv[g4 * 4 + u];
                if (dm && krow > c32) v = -__builtin_inff();
                float e = __expf(v);
                lsum += e;
                pk[u] = f2bf(e);
            }
            *(us4*)&myPs[c32 * 36 + 8 * g4 + 4 * l5] = pk;
        }
        // O^T += V^T P^T (same-wave LDS roundtrip)
        #pragma unroll
        for (int k2 = 0; k2 < 2; ++k2) {
            us4 plo = *(const us4*)&myPs[c32 * 36 + k2 * 16 + l5 * 8];
            us4 phi = *(const us4*)&myPs[c32 * 36 + k2 * 16 + l5 * 8 + 4];
            us8 pc;
            pc[0]=plo[0]; pc[1]=plo[1]; pc[2]=plo[2]; pc[3]=plo[3];
            pc[4]=phi[0]; pc[5]=phi[1]; pc[6]=phi[2]; pc[7]=phi[3];
            s8v Pb = __builtin_bit_cast(s8v, pc);
            #pragma unroll
            for (int nt = 0; nt < 4; ++nt)
                O[nt] = __builtin_amdgcn_mfma_f32_32x32x16_bf16(Vf[k2][nt], Pb, O[nt], 0, 0, 0);
        }
    }

    // ---- combine partial l across waves ----
    float lw = lsum + __shfl_xor(lsum, 32);      // per-lane q=c32, this wave
    if (l5 == 0) Lsums[w * 32 + c32] = lw;
    __syncthreads();
    const float inv = 1.0f / (Lsums[c32] + Lsums[32 + c32] +
                              Lsums[64 + c32] + Lsums[96 + c32]);

    // ---- combine partial O across waves, chunked by nt (16 KB buffer) ----
    #pragma unroll
    for (int nt = 0; nt < 4; ++nt) {
        #pragma unroll
        for (int g4 = 0; g4 < 4; ++g4) {
            f4v v = { O[nt][g4 * 4 + 0], O[nt][g4 * 4 + 1],
                      O[nt][g4 * 4 + 2], O[nt][g4 * 4 + 3] };
            *(f4v*)&Ob[((w * 4 + g4) * 64 + L) * 4] = v;     // contiguous/wave
        }
        __syncthreads();
        if (w == nt) {
            #pragma unroll
            for (int g4 = 0; g4 < 4; ++g4) {
                f4v a0 = *(const f4v*)&Ob[((0 * 4 + g4) * 64 + L) * 4];
                f4v a1 = *(const f4v*)&Ob[((1 * 4 + g4) * 64 + L) * 4];
                f4v a2 = *(const f4v*)&Ob[((2 * 4 + g4) * 64 + L) * 4];
                f4v a3 = *(const f4v*)&Ob[((3 * 4 + g4) * 64 + L) * 4];
                f4v r = (a0 + a1) + (a2 + a3);
                r[0] *= inv; r[1] *= inv; r[2] *= inv; r[3] *= inv;
                *(f4v*)(out + qrow * kH + nt * 32 + 8 * g4 + 4 * l5) = r;
            }
        }
        __syncthreads();   // buffer free before next chunk
    }
}

extern "C" void kernel_launch(void* const* d_in, const int* in_sizes, int n_in,
                              void* d_out, int out_size, void* d_ws, size_t ws_size,
                              hipStream_t stream) {
    const float* X  = (const float*)d_in[0];
    const float* Wq = (const float*)d_in[1];
    const float* Wk = (const float*)d_in[2];
    const float* Wv = (const float*)d_in[3];
    unsigned short* ws = (unsigned short*)d_ws;          // q | k | v^T bf16 (25.2 MB)
    unsigned short* Wt = ws + (size_t)3 * kBS * kH;      // +768 KB transposed weights
    float* out = (float*)d_out;

    prep_w<<<dim3(3, 16), 256, 0, stream>>>(Wq, Wk, Wv, Wt);
    qkv_gemm<<<dim3(kBS / 64), 256, 0, stream>>>(X, Wt, ws);
    attn<<<dim3(kB, 64), 256, 0, stream>>>(ws, out);
}

// Round 5
// 286.565 us; speedup vs baseline: 1.4306x; 1.4306x over previous
//
#include <hip/hip_runtime.h>
#include <hip/hip_bf16.h>

#define kB 16
#define kS 2048
#define kD 1024
#define kH 128
#define kBS (kB * kS)

typedef short s8v __attribute__((ext_vector_type(8)));
typedef float f4v __attribute__((ext_vector_type(4)));
typedef float f16v __attribute__((ext_vector_type(16)));
typedef unsigned short us4 __attribute__((ext_vector_type(4)));
typedef unsigned short us8 __attribute__((ext_vector_type(8)));

__device__ __forceinline__ unsigned short f2bf(float f) {
    __hip_bfloat16 h = __float2bfloat16(f);
    return __builtin_bit_cast(unsigned short, h);
}

// async global->LDS DMA, 16B per lane, LDS dest = wave-uniform base + lane*16
__device__ __forceinline__ void gl16(const void* g, void* l) {
    __builtin_amdgcn_global_load_lds(
        (const __attribute__((address_space(1))) unsigned int*)g,
        (__attribute__((address_space(3))) unsigned int*)l, 16, 0, 0);
}

// ---------------------------------------------------------------------------
// Kernel 0: W[1024][128] fp32 -> Wt[384][1024] bf16 (transposed, q|k|v).
// Wq pre-scaled by H^-0.5.  (unchanged)
// ---------------------------------------------------------------------------
__global__ void prep_w(const float* __restrict__ Wq, const float* __restrict__ Wk,
                       const float* __restrict__ Wv, unsigned short* __restrict__ Wt)
{
    const int g = blockIdx.x;
    const float* W = (g == 0) ? Wq : (g == 1) ? Wk : Wv;
    const float sc = (g == 0) ? 0.08838834764831845f : 1.0f;  // 128^-0.5 folded into Wq
    unsigned short* o = Wt + (size_t)g * 128 * 1024;
    const int t = threadIdx.x;
    const int n = t & 127;
    const int half = t >> 7;
    const int kbase = blockIdx.y * 64 + half * 32;
    #pragma unroll
    for (int c = 0; c < 4; ++c) {
        int kb = kbase + c * 8;
        us8 v;
        #pragma unroll
        for (int j = 0; j < 8; ++j) v[j] = f2bf(W[(size_t)(kb + j) * kH + n] * sc);
        *(us8*)(o + (size_t)n * 1024 + kb) = v;
    }
}

// ---------------------------------------------------------------------------
// Kernel 1 (R9): fused QKV GEMM, m97-shape. BM=128 x BN=384, BK=64, 16 steps.
// 8 waves (2m x 4n), per-wave 64x96 = acc[4][6]. 256 blocks = 1/CU.
// LDS (shorts): A dbuf 2x[128][68] @ 0/8704 (pad-68: conflict-free reads);
//               B dbuf 2x[384][64] @ 17408/41984, LINEAR for DMA with
//               XOR chunk swizzle (pos c holds global chunk c^(row&7));
//               source address pre-swizzled (rule: both-sides-or-neither).
// Per step/wave: 4 X float4 loads + 2 A us8 ds_writes + 6 B DMA issues;
// 20 ds_read_b128 + 48 MFMA. ONE barrier per step.
// ---------------------------------------------------------------------------
#define AOFF(b_) ((b_) * 8704)
#define BOFF(b_) (17408 + (b_) * 24576)

#define STAGE(b_, tt_) do {                                                   \
    _Pragma("unroll")                                                         \
    for (int u = 0; u < 4; ++u)                                               \
        xa[u] = *(const float4*)(Xp + (tt_) * 64 + u * 4);                    \
    _Pragma("unroll")                                                         \
    for (int ci = 0; ci < 6; ++ci) {                                          \
        const int rb = w * 48 + ci * 8;                                       \
        gl16(WpL + (size_t)rb * 1024 + (tt_) * 64, &smem[BOFF(b_) + rb * 64]);\
    }                                                                         \
} while (0)

#define AWRITE(b_) do {                                                       \
    _Pragma("unroll")                                                         \
    for (int u2 = 0; u2 < 2; ++u2) {                                          \
        us8 aw;                                                               \
        aw[0] = f2bf(xa[2*u2].x);   aw[1] = f2bf(xa[2*u2].y);                 \
        aw[2] = f2bf(xa[2*u2].z);   aw[3] = f2bf(xa[2*u2].w);                 \
        aw[4] = f2bf(xa[2*u2+1].x); aw[5] = f2bf(xa[2*u2+1].y);               \
        aw[6] = f2bf(xa[2*u2+1].z); aw[7] = f2bf(xa[2*u2+1].w);               \
        *(us8*)&smem[AOFF(b_) + arow * 68 + ac16 + u2 * 8] = aw;              \
    }                                                                         \
} while (0)

__global__ __launch_bounds__(512, 2) void qkv_gemm(
    const float* __restrict__ X, const unsigned short* __restrict__ Wt,
    unsigned short* __restrict__ ws)
{
    __shared__ __align__(16) unsigned short smem[66560];   // 133 KB

    const int t    = threadIdx.x;
    const int L    = t & 63;
    const int w    = t >> 6;                 // wave 0..7
    const int wr   = w >> 2;                 // m-half 0..1
    const int wc   = w & 3;                  // n-quarter 0..3
    const int col  = L & 15;
    const int quad = L >> 4;
    const int m0   = blockIdx.x * 128;

    f4v acc[4][6];
    #pragma unroll
    for (int i = 0; i < 4; ++i)
        #pragma unroll
        for (int j = 0; j < 6; ++j) { f4v z = {0.f, 0.f, 0.f, 0.f}; acc[i][j] = z; }

    const int arow = t >> 2;                 // 0..127
    const int ac16 = (t & 3) * 16;           // k-base (shorts/floats) 0,16,32,48
    const float* Xp = X + (size_t)(m0 + arow) * kD + ac16;
    // B DMA source, pre-swizzled: lane L covers row rb+(L>>3), LDS chunk (L&7)
    // which must hold global chunk (L&7)^(L>>3)  (row&7 == L>>3 since rb%8==0)
    const unsigned short* WpL = Wt + (size_t)(L >> 3) * 1024
                                + (((L & 7) ^ (L >> 3)) * 8);

    float4 xa[4];

    STAGE(0, 0);
    AWRITE(0);
    __syncthreads();     // drains tile-0 DMAs

    #pragma unroll 2
    for (int tt = 0; tt < 16; ++tt) {
        const int cb = tt & 1;
        if (tt < 15) STAGE(cb ^ 1, tt + 1);     // fire-and-forget next tile
        const int ab = AOFF(cb), bbs = BOFF(cb);
        #pragma unroll
        for (int ks = 0; ks < 2; ++ks) {
            s8v Af[4], Bf[6];
            #pragma unroll
            for (int i = 0; i < 4; ++i)
                Af[i] = *(const s8v*)&smem[ab + (wr * 64 + i * 16 + col) * 68
                                           + ks * 32 + quad * 8];
            const int swz = (((ks * 4 + quad) ^ (col & 7)) * 8);
            #pragma unroll
            for (int j = 0; j < 6; ++j) {
                const int n = wc * 96 + j * 16 + col;
                Bf[j] = *(const s8v*)&smem[bbs + n * 64 + swz];
            }
            #pragma unroll
            for (int i = 0; i < 4; ++i)
                #pragma unroll
                for (int j = 0; j < 6; ++j)
                    acc[i][j] = __builtin_amdgcn_mfma_f32_16x16x32_bf16(
                        Af[i], Bf[j], acc[i][j], 0, 0, 0);
        }
        if (tt < 15) AWRITE(cb ^ 1);
        __syncthreads();
    }

    // ---- epilogue: repack via LDS, write q/k [s][h] and v^T [b][h][s] ----
    for (int g = 0; g < 3; ++g) {
        __syncthreads();
        #pragma unroll
        for (int j = 0; j < 6; ++j) {
            if (((96 * wc + 16 * j) >> 7) != g) continue;   // wave-uniform
            int n = 96 * wc + 16 * j + col;
            if (g < 2) {
                int ng = n - g * 128;
                #pragma unroll
                for (int i = 0; i < 4; ++i)
                    #pragma unroll
                    for (int rg = 0; rg < 4; ++rg)
                        smem[(wr * 64 + i * 16 + quad * 4 + rg) * 136 + ng] =
                            f2bf(acc[i][j][rg]);
            } else {
                int h = n - 256;
                #pragma unroll
                for (int i = 0; i < 4; ++i) {
                    us4 pk = { f2bf(acc[i][j][0]), f2bf(acc[i][j][1]),
                               f2bf(acc[i][j][2]), f2bf(acc[i][j][3]) };
                    *(us4*)&smem[h * 136 + wr * 64 + i * 16 + quad * 4] = pk;
                }
            }
        }
        __syncthreads();
        if (g < 2) {
            unsigned short* outp = ws + (size_t)g * kBS * kH;
            int row = t >> 2, hc = (t & 3) * 32;
            #pragma unroll
            for (int u = 0; u < 4; ++u) {
                us8 v = *(const us8*)&smem[row * 136 + hc + u * 8];
                *(us8*)(outp + (size_t)(m0 + row) * kH + hc + u * 8) = v;
            }
        } else {
            unsigned short* vtp = ws + (size_t)2 * kBS * kH;
            int h = t >> 2, sc2 = (t & 3) * 32;
            int bb = m0 >> 11, sl = m0 & 2047;
            #pragma unroll
            for (int u = 0; u < 4; ++u) {
                us8 v = *(const us8*)&smem[h * 136 + sc2 + u * 8];
                *(us8*)(vtp + ((size_t)bb * kH + h) * kS + sl + sc2 + u * 8) = v;
            }
        }
    }
}

// ---------------------------------------------------------------------------
// Kernel 2 (R9): causal attention — 2-wave in-block SPLIT-K per q-slot.
// Wave w takes tiles T ≡ w (mod 2). Plain-exp streaming softmax: partial O
// and l combine by addition (LDS). __launch_bounds__(128,2) -> 256-VGPR cap
// (R8's 64-VGPR spill disaster fixed). 1024 blocks x 2 waves = 2 waves/SIMD.
// ---------------------------------------------------------------------------
__global__ __launch_bounds__(128, 2) void attn(
    const unsigned short* __restrict__ ws, float* __restrict__ out)
{
    __shared__ float Ob[2048];               // 8 KB combine chunk
    __shared__ float Lsums[64];
    __shared__ unsigned short Ps[2 * 1152];  // per-wave P[32][36]

    const int t   = threadIdx.x;
    const int w   = t >> 6;                  // wave 0..1
    const int L   = t & 63;
    const int l5  = L >> 5;
    const int c32 = L & 31;
    const int b   = blockIdx.x;
    const int g2  = blockIdx.y >> 4, ii = blockIdx.y & 15;
    const int s   = (g2 == 0) ? 63 - ii : (g2 == 1) ? 32 + ii
                  : (g2 == 2) ? 31 - ii : ii;          // bijective onto 0..63

    const unsigned short* qp = ws;
    const unsigned short* kp = ws + (size_t)kBS * kH + (size_t)b * kS * kH;
    const unsigned short* vt = ws + (size_t)2 * kBS * kH + (size_t)b * kH * kS;

    const size_t qrow = (size_t)b * kS + s * 32 + c32;
    unsigned short* myPs = Ps + w * 1152;

    // Q B-frags (n=lane&31 -> q=c32, k=l5*8+j at k-offset ks*16)
    s8v Qf[8];
    #pragma unroll
    for (int ks = 0; ks < 8; ++ks)
        Qf[ks] = *(const s8v*)(qp + qrow * kH + ks * 16 + l5 * 8);

    f16v O[4];
    #pragma unroll
    for (int nt = 0; nt < 4; ++nt)
        #pragma unroll
        for (int r = 0; r < 16; ++r) O[nt][r] = 0.f;
    float lsum = 0.f;

    // prefetch first K tile of this wave
    s8v Kf[8];
    #pragma unroll
    for (int ks = 0; ks < 8; ++ks)
        Kf[ks] = *(const s8v*)(kp + (size_t)(w * 32 + c32) * kH + ks * 16 + l5 * 8);

    for (int T = w; T <= s; T += 2) {
        const int kb = T * 32;
        // V^T A-frags (m = h within 32-group = c32, k = key)
        s8v Vf[2][4];
        #pragma unroll
        for (int k2 = 0; k2 < 2; ++k2)
            #pragma unroll
            for (int nt = 0; nt < 4; ++nt)
                Vf[k2][nt] = *(const s8v*)(vt + (size_t)(nt * 32 + c32) * kS
                                           + kb + k2 * 16 + l5 * 8);
        // S^T = K Q^T
        f16v Sv;
        #pragma unroll
        for (int r = 0; r < 16; ++r) Sv[r] = 0.f;
        #pragma unroll
        for (int ks = 0; ks < 8; ++ks)
            Sv = __builtin_amdgcn_mfma_f32_32x32x16_bf16(Kf[ks], Qf[ks], Sv, 0, 0, 0);
        // prefetch this wave's next K tile (stride 2 tiles = +64 rows)
        if (T + 2 <= s) {
            #pragma unroll
            for (int ks = 0; ks < 8; ++ks)
                Kf[ks] = *(const s8v*)(kp + (size_t)(kb + 64 + c32) * kH + ks * 16 + l5 * 8);
        }
        // mask (diagonal tile) + exp + P store; lane holds 16 keys of q=c32
        const bool dm = (T == s);
        #pragma unroll
        for (int g4 = 0; g4 < 4; ++g4) {
            us4 pk;
            #pragma unroll
            for (int u = 0; u < 4; ++u) {
                int krow = u + 8 * g4 + 4 * l5;       // C-layout row = key
                float v = Sv[g4 * 4 + u];
                if (dm && krow > c32) v = -__builtin_inff();
                float e = __expf(v);
                lsum += e;
                pk[u] = f2bf(e);
            }
            *(us4*)&myPs[c32 * 36 + 8 * g4 + 4 * l5] = pk;
        }
        // O^T += V^T P^T (same-wave LDS roundtrip)
        #pragma unroll
        for (int k2 = 0; k2 < 2; ++k2) {
            us4 plo = *(const us4*)&myPs[c32 * 36 + k2 * 16 + l5 * 8];
            us4 phi = *(const us4*)&myPs[c32 * 36 + k2 * 16 + l5 * 8 + 4];
            us8 pc;
            pc[0]=plo[0]; pc[1]=plo[1]; pc[2]=plo[2]; pc[3]=plo[3];
            pc[4]=phi[0]; pc[5]=phi[1]; pc[6]=phi[2]; pc[7]=phi[3];
            s8v Pb = __builtin_bit_cast(s8v, pc);
            #pragma unroll
            for (int nt = 0; nt < 4; ++nt)
                O[nt] = __builtin_amdgcn_mfma_f32_32x32x16_bf16(Vf[k2][nt], Pb, O[nt], 0, 0, 0);
        }
    }

    // ---- combine partial l across the two waves ----
    float lw = lsum + __shfl_xor(lsum, 32);
    if (l5 == 0) Lsums[w * 32 + c32] = lw;
    __syncthreads();
    const float inv = 1.0f / (Lsums[c32] + Lsums[32 + c32]);

    // ---- combine partial O across waves, chunked by nt (8 KB buffer) ----
    #pragma unroll
    for (int nt = 0; nt < 4; ++nt) {
        #pragma unroll
        for (int g4 = 0; g4 < 4; ++g4) {
            f4v v = { O[nt][g4 * 4 + 0], O[nt][g4 * 4 + 1],
                      O[nt][g4 * 4 + 2], O[nt][g4 * 4 + 3] };
            *(f4v*)&Ob[((w * 4 + g4) * 64 + L) * 4] = v;
        }
        __syncthreads();
        if (w == (nt & 1)) {
            #pragma unroll
            for (int g4 = 0; g4 < 4; ++g4) {
                f4v a0 = *(const f4v*)&Ob[((0 * 4 + g4) * 64 + L) * 4];
                f4v a1 = *(const f4v*)&Ob[((1 * 4 + g4) * 64 + L) * 4];
                f4v r = a0 + a1;
                r[0] *= inv; r[1] *= inv; r[2] *= inv; r[3] *= inv;
                *(f4v*)(out + qrow * kH + nt * 32 + 8 * g4 + 4 * l5) = r;
            }
        }
        __syncthreads();
    }
}

extern "C" void kernel_launch(void* const* d_in, const int* in_sizes, int n_in,
                              void* d_out, int out_size, void* d_ws, size_t ws_size,
                              hipStream_t stream) {
    const float* X  = (const float*)d_in[0];
    const float* Wq = (const float*)d_in[1];
    const float* Wk = (const float*)d_in[2];
    const float* Wv = (const float*)d_in[3];
    unsigned short* ws = (unsigned short*)d_ws;          // q | k | v^T bf16 (25.2 MB)
    unsigned short* Wt = ws + (size_t)3 * kBS * kH;      // +768 KB transposed weights
    float* out = (float*)d_out;

    prep_w<<<dim3(3, 16), 256, 0, stream>>>(Wq, Wk, Wv, Wt);
    qkv_gemm<<<dim3(kBS / 128), 512, 0, stream>>>(X, Wt, ws);
    attn<<<dim3(kB, 64), 128, 0, stream>>>(ws, out);
}